// Round 8
// baseline (190.995 us; speedup 1.0000x reference)
//
#include <hip/hip_runtime.h>

typedef __attribute__((ext_vector_type(8))) short short8;
typedef __attribute__((ext_vector_type(4))) float f32x4;
typedef unsigned short u16;
typedef unsigned int u32;

#define XH 114
#define XW 114
#define CINC 64
#define COUT 128
#define OH 112
#define OW 112
#define NB 32
#define KTOT 576      // CIN*9
#define TILEB 58368   // 4*114*64*2 bytes per B tile

static __device__ __forceinline__ u16 f2bf(float f) {
    u32 x = __float_as_uint(f);
    u32 r = (x + 0x7fffu + ((x >> 16) & 1u)) >> 16;
    return (u16)r;
}

#define MFMA16(a, b, c) __builtin_amdgcn_mfma_f32_16x16x32_bf16((a), (b), (c), 0, 0, 0)

// weights -> bf16, K reordered to (kh,kw,ci):  wbf[o][(kh*3+kw)*64 + ci]
__global__ __launch_bounds__(256) void wcvt_reord(const float* __restrict__ w,
                                                  u16* __restrict__ wbf) {
    int i = blockIdx.x * 256 + threadIdx.x;   // 73728 total, exact
    int o = i / KTOT;
    int rem = i - o * KTOT;
    int khkw = rem >> 6;
    int ci = rem & 63;
    wbf[i] = f2bf(w[(o * CINC + ci) * 9 + khkw]);
}

// Persistent fused conv: 256 blocks x 512 thr; 7 row-pair tiles per block.
// Staging reads NCHW f32 directly (lane->w coalesced), converts, writes the
// swizzled [pix][ci] LDS layout. A (weights) in registers for whole kernel.
// Operand-swapped MFMA: pixels=A rows, couts=B cols -> dwordx4 output stores.
__global__ __launch_bounds__(512, 2) void conv_direct(const float* __restrict__ x,
                                                      const u16* __restrict__ wbf,
                                                      const float* __restrict__ bias,
                                                      float* __restrict__ out) {
    __shared__ u16 lds[2 * 4 * XW * CINC];   // 116736 B
    char* ldsc = (char*)lds;

    const int tid  = threadIdx.x;
    const int lane = tid & 63;
    const int wv   = tid >> 6;        // 0..7
    const int l16  = lane & 15;
    const int lhi  = lane >> 4;
    const int wm   = wv & 3;          // cout group [wm*32, wm*32+32)
    const int wn   = wv >> 2;         // output row within pair

    int bidx = blockIdx.x;
    { int xcd = bidx & 7; bidx = xcd * 32 + (bidx >> 3); }   // 256 = 8*32 bijective
    const int t0g = bidx * 7;

    // ---- A prologue: whole per-wave weight set in VGPRs (36 short8 = 144) ----
    const u16* wrow0 = wbf + (wm * 32 + l16) * KTOT + lhi * 8;
    const u16* wrow1 = wrow0 + 16 * KTOT;
    short8 areg[18][2];
    #pragma unroll
    for (int t = 0; t < 18; ++t) {
        areg[t][0] = *(const short8*)(wrow0 + t * 32);
        areg[t][1] = *(const short8*)(wrow1 + t * 32);
    }

    // ---- fused transpose-convert staging ----
    // wave -> input row r = wv>>1, ci-pairs cp0..cp0+15 (cp0 = (wv&1)*16)
    // lanes -> w (two halves: w=lane, w=64+lane[<50]) => coalesced dword loads
    auto STAGE = [&](int tg, int bufsel) {
        const int bb  = tg / 56;
        const int hh0 = (tg - bb * 56) * 2;
        char* dst = ldsc + bufsel * TILEB;
        const int r  = wv >> 1;
        const int cp0 = (wv & 1) * 16;
        const float* xrow = x + ((size_t)(bb * CINC) * XH + (hh0 + r)) * XW;
        const int hb = 2 * (hh0 + r);
        #pragma unroll
        for (int k = 0; k < 16; ++k) {
            const int cp = cp0 + k;
            const float* r0 = xrow + (size_t)(2 * cp) * (XH * XW);
            const float* r1 = r0 + XH * XW;
            const int slotb = cp >> 2;              // (2cp)>>3
            const int cilo  = ((2 * cp) & 7) << 1;
            {
                const int w = lane;
                u32 pk = (u32)f2bf(r0[w]) | ((u32)f2bf(r1[w]) << 16);
                const int swz = slotb ^ ((hb + w) & 7);
                *(u32*)(dst + ((((r * XW + w) << 7) | (swz << 4) | cilo))) = pk;
            }
            if (lane < XW - 64) {
                const int w = 64 + lane;
                u32 pk = (u32)f2bf(r0[w]) | ((u32)f2bf(r1[w]) << 16);
                const int swz = slotb ^ ((hb + w) & 7);
                *(u32*)(dst + ((((r * XW + w) << 7) | (swz << 4) | cilo))) = pk;
            }
        }
    };

    const f32x4 zero = {0.f, 0.f, 0.f, 0.f};

    auto COMPUTE = [&](int tg, int bufsel) {
        const int bb  = tg / 56;
        const int hh0 = (tg - bb * 56) * 2;
        char* buf = ldsc + bufsel * TILEB;

        f32x4 acc[2][7];
        #pragma unroll
        for (int mf = 0; mf < 2; ++mf)
            #pragma unroll
            for (int nf = 0; nf < 7; ++nf) acc[mf][nf] = zero;

        #pragma unroll
        for (int tt = 0; tt < 9; ++tt) {
            const int kh = tt / 3;
            const int kw = tt - kh * 3;
            const int r  = wn + kh;                         // tile row 0..3
            const int pix0 = r * XW + kw + l16;
            const int hash = (2 * (hh0 + r) + kw + l16) & 7;   // nf-invariant
            const int ba0 = (pix0 << 7) + ((lhi ^ hash) << 4);

            __builtin_amdgcn_s_setprio(1);
            #pragma unroll
            for (int nf = 0; nf < 7; ++nf) {
                short8 bf = *(const short8*)(buf + ba0 + nf * 2048);
                acc[0][nf] = MFMA16(bf, areg[2 * tt][0], acc[0][nf]);
                acc[1][nf] = MFMA16(bf, areg[2 * tt][1], acc[1][nf]);
            }
            __builtin_amdgcn_s_setprio(0);

            __builtin_amdgcn_s_setprio(1);
            #pragma unroll
            for (int nf = 0; nf < 7; ++nf) {
                short8 bf = *(const short8*)(buf + (ba0 ^ 0x40) + nf * 2048);
                acc[0][nf] = MFMA16(bf, areg[2 * tt + 1][0], acc[0][nf]);
                acc[1][nf] = MFMA16(bf, areg[2 * tt + 1][1], acc[1][nf]);
            }
            __builtin_amdgcn_s_setprio(0);
        }

        // epilogue: D row = pixel (lhi*4+j), col = cout (l16) -> dwordx4 stores
        #pragma unroll
        for (int mf = 0; mf < 2; ++mf) {
            const int o = wm * 32 + mf * 16 + l16;
            const float bv = bias[o];
            float* po = out + ((size_t)bb * COUT + o) * (OH * OW) + (hh0 + wn) * OW;
            #pragma unroll
            for (int nf = 0; nf < 7; ++nf) {
                f32x4 v = acc[mf][nf];
                v[0] += bv; v[1] += bv; v[2] += bv; v[3] += bv;
                *(f32x4*)(po + nf * 16 + lhi * 4) = v;
            }
        }
    };

    STAGE(t0g, 0);

    #pragma unroll 1
    for (int i = 0; i < 7; ++i) {
        __syncthreads();
        const bool sfirst = (wv < 4);
        if (i < 6 && sfirst) STAGE(t0g + i + 1, (i + 1) & 1);
        COMPUTE(t0g + i, i & 1);
        if (i < 6 && !sfirst) STAGE(t0g + i + 1, (i + 1) & 1);
    }
}

// ---------------- fallback (R0 kernel, needs only 147456 B ws) ----------------

#define BK 32
#define NSTEP 18
#define LDB 40

__global__ __launch_bounds__(256) void wcvt_ident(const float* __restrict__ w,
                                                  u16* __restrict__ wbf) {
    int i = blockIdx.x * 256 + threadIdx.x;
    if (i < COUT * KTOT) wbf[i] = f2bf(w[i]);
}

__global__ __launch_bounds__(256) void conv_fb(const float* __restrict__ x,
                                               const u16* __restrict__ wbf,
                                               const float* __restrict__ bias,
                                               float* __restrict__ out) {
    __shared__ u16 ldsB[OW * LDB];
    const int tid = threadIdx.x;
    int bid = blockIdx.x;
    { int xcd = bid & 7; bid = xcd * 448 + (bid >> 3); }
    const int b = bid / OH;
    const int h = bid - b * OH;
    const float* xbp = x + (size_t)b * (CINC * XH * XW);
    float* outb = out + (size_t)b * (COUT * OH * OW) + h * OW;
    const int lane = tid & 63, wv = tid >> 6, l16 = lane & 15, lhi = lane >> 4;
    const int m0 = wv * 32;
    const int sk = tid >> 3, sn0 = (tid & 7) * 14;
    f32x4 acc[2][7];
    const f32x4 zero = {0.f, 0.f, 0.f, 0.f};
    #pragma unroll
    for (int i = 0; i < 2; ++i)
        #pragma unroll
        for (int j = 0; j < 7; ++j) acc[i][j] = zero;
    for (int t = 0; t < NSTEP; ++t) {
        const int kg = t * BK + sk;
        const int ci = kg / 9;
        const int r9 = kg - ci * 9;
        const int kh = r9 / 3, kw = r9 - (r9 / 3) * 3;
        const float* src = xbp + ((size_t)ci * XH + (h + kh)) * XW + kw + sn0;
        __syncthreads();
        #pragma unroll
        for (int i = 0; i < 14; ++i) ldsB[(sn0 + i) * LDB + sk] = f2bf(src[i]);
        __syncthreads();
        short8 afrag[2];
        #pragma unroll
        for (int mf = 0; mf < 2; ++mf)
            afrag[mf] = *(const short8*)(wbf + (m0 + mf * 16 + l16) * KTOT + t * BK + lhi * 8);
        #pragma unroll
        for (int nf = 0; nf < 7; ++nf) {
            short8 bfrag = *(const short8*)&ldsB[(nf * 16 + l16) * LDB + lhi * 8];
            acc[0][nf] = MFMA16(afrag[0], bfrag, acc[0][nf]);
            acc[1][nf] = MFMA16(afrag[1], bfrag, acc[1][nf]);
        }
    }
    #pragma unroll
    for (int mf = 0; mf < 2; ++mf)
        #pragma unroll
        for (int j = 0; j < 4; ++j) {
            const int o = m0 + mf * 16 + lhi * 4 + j;
            const float bv = bias[o];
            #pragma unroll
            for (int nf = 0; nf < 7; ++nf)
                outb[(size_t)o * (OH * OW) + nf * 16 + l16] = acc[mf][nf][j] + bv;
        }
}

extern "C" void kernel_launch(void* const* d_in, const int* in_sizes, int n_in,
                              void* d_out, int out_size, void* d_ws, size_t ws_size,
                              hipStream_t stream) {
    const float* x    = (const float*)d_in[0];
    const float* w    = (const float*)d_in[3];
    const float* bias = (const float*)d_in[4];
    float* out = (float*)d_out;

    const size_t WBYTES = (size_t)COUT * KTOT * 2;   // 147456
    if (ws_size >= WBYTES) {
        u16* wbf = (u16*)d_ws;
        wcvt_reord<<<(COUT * KTOT) / 256, 256, 0, stream>>>(w, wbf);
        conv_direct<<<256, 512, 0, stream>>>(x, wbf, bias, out);
    } else {
        u16* wbf = (u16*)d_ws;
        wcvt_ident<<<(COUT * KTOT + 255) / 256, 256, 0, stream>>>(w, wbf);
        conv_fb<<<NB * OH, 256, 0, stream>>>(x, wbf, bias, out);
    }
}

// Round 9
// 120.926 us; speedup vs baseline: 1.5794x; 1.5794x over previous
//
#include <hip/hip_runtime.h>

typedef __attribute__((ext_vector_type(8))) short short8;
typedef __attribute__((ext_vector_type(4))) float f32x4;
typedef __attribute__((ext_vector_type(4))) unsigned int u32x4;
typedef unsigned short u16;
typedef unsigned int u32;

#define XH 114
#define XW 114
#define CINC 64
#define COUT 128
#define OH 112
#define OW 112
#define NB 32
#define KTOT 576      // CIN*9
#define TILEB 58368   // 4*114*64*2 bytes per tile

static __device__ __forceinline__ u16 f2bf(float f) {
    u32 x = __float_as_uint(f);
    u32 r = (x + 0x7fffu + ((x >> 16) & 1u)) >> 16;
    return (u16)r;
}

#define MFMA16(a, b, c) __builtin_amdgcn_mfma_f32_16x16x32_bf16((a), (b), (c), 0, 0, 0)

static __device__ __forceinline__ void gload16(const void* g, void* l) {
    __builtin_amdgcn_global_load_lds(
        (const __attribute__((address_space(1))) unsigned int*)g,
        (__attribute__((address_space(3))) unsigned int*)l, 16, 0, 0);
}

// ---------------- fast path ----------------

// Merged pre-pass. Blocks [0,3648): x NCHW f32 -> xb bf16, swizzle baked:
//   xb[(b*114+h)*7296 + w*64 + (c8 ^ ((2h+w)&7))*8 + e] = x[b][8*c8+e][h][w]
// Blocks [3648,3936): weights -> bf16, K reordered to (kh,kw,ci).
__global__ __launch_bounds__(256) void prep(const float* __restrict__ x,
                                            const float* __restrict__ w,
                                            u16* __restrict__ xb,
                                            u16* __restrict__ wbf) {
    const int tid = threadIdx.x;
    const int blk = blockIdx.x;
    if (blk >= NB * XH) {
        int i = (blk - NB * XH) * 256 + tid;   // 73728 total, exact
        int o = i / KTOT;
        int rem = i - o * KTOT;
        int khkw = rem >> 6;
        int ci = rem & 63;
        wbf[i] = f2bf(w[(o * CINC + ci) * 9 + khkw]);
        return;
    }
    __shared__ u16 tile[XW * 70];   // [w][ci], u16 stride 70 (dword 35, coprime 32)
    const int b = blk / XH;
    const int h = blk - b * XH;

    #pragma unroll
    for (int it = 0; it < 15; ++it) {
        int idx = it * 256 + tid;
        if (idx < 32 * XW) {
            int cp = idx / XW;                  // 0..31
            int w_ = idx - cp * XW;
            const float* s0 = x + ((size_t)(b * CINC + 2 * cp) * XH + h) * XW + w_;
            float a = s0[0];
            float c = s0[XH * XW];
            u32 pk = (u32)f2bf(a) | ((u32)f2bf(c) << 16);
            *(u32*)&tile[w_ * 70 + 2 * cp] = pk;
        }
    }
    __syncthreads();

    u16* dstrow = xb + (size_t)(b * XH + h) * (XW * CINC);
    #pragma unroll
    for (int p2 = 0; p2 < 4; ++p2) {
        int task = p2 * 256 + tid;
        if (task < XW * 8) {
            int w_ = task >> 3;
            int c8 = task & 7;
            const u32* s = (const u32*)&tile[w_ * 70 + c8 * 8];
            u32x4 v = {s[0], s[1], s[2], s[3]};
            int slot = c8 ^ ((2 * h + w_) & 7);
            *(u32x4*)(dstrow + w_ * CINC + slot * 8) = v;
        }
    }
}

// Persistent implicit-GEMM conv: 256 blocks x 512 thr; 7 row-pair tiles each.
// A (weights) in registers; B double-buffered LDS via global_load_lds.
// Operand-swapped MFMA (pixels = C rows) -> dwordx4 epilogue stores.
// End-of-iter barrier uses counted vmcnt(14): staging retired, stores float.
__global__ __launch_bounds__(512, 2) void conv_pers2(const u16* __restrict__ xb,
                                                     const u16* __restrict__ wbf,
                                                     const float* __restrict__ bias,
                                                     float* __restrict__ out) {
    __shared__ u16 lds[2 * 4 * XW * CINC];   // 116736 B
    char* ldsc = (char*)lds;

    const int tid  = threadIdx.x;
    const int lane = tid & 63;
    const int wv   = tid >> 6;        // 0..7
    const int l16  = lane & 15;
    const int lhi  = lane >> 4;
    const int wm   = wv & 3;          // cout group [wm*32, wm*32+32)
    const int wn   = wv >> 2;         // output row within pair

    int bidx = blockIdx.x;
    { int xcd = bidx & 7; bidx = xcd * 32 + (bidx >> 3); }   // 256 = 8*32 bijective
    const int t0g = bidx * 7;

    // ---- prologue: weights + bias in registers ----
    const u16* wrow0 = wbf + (wm * 32 + l16) * KTOT + lhi * 8;
    const u16* wrow1 = wrow0 + 16 * KTOT;
    short8 areg[18][2];
    #pragma unroll
    for (int t = 0; t < 18; ++t) {
        areg[t][0] = *(const short8*)(wrow0 + t * 32);
        areg[t][1] = *(const short8*)(wrow1 + t * 32);
    }
    const float bv0 = bias[wm * 32 + l16];
    const float bv1 = bias[wm * 32 + 16 + l16];

    // ---- stage tile 0 into buffer 0 ----
    {
        const int tg = t0g;
        const char* src = (const char*)(xb + (size_t)((tg / 56) * XH + (tg % 56) * 2) * (XW * CINC));
        #pragma unroll
        for (int it = 0; it < 8; ++it) {
            int off = it * 8192 + wv * 1024;
            if (off < TILEB) gload16(src + off + lane * 16, ldsc + off);
        }
    }
    __syncthreads();   // full drain once (covers areg + tile-0 staging)

    const f32x4 zero = {0.f, 0.f, 0.f, 0.f};

    #pragma unroll 1
    for (int i = 0; i < 7; ++i) {
        // issue next tile's staging (retires before end-of-iter barrier)
        if (i < 6) {
            const int tg = t0g + i + 1;
            const char* src = (const char*)(xb + (size_t)((tg / 56) * XH + (tg % 56) * 2) * (XW * CINC));
            char* dstb = ldsc + ((i + 1) & 1) * TILEB;
            #pragma unroll
            for (int it = 0; it < 8; ++it) {
                int off = it * 8192 + wv * 1024;
                if (off < TILEB) gload16(src + off + lane * 16, dstb + off);
            }
        }

        const int tg = t0g + i;
        const int bb  = tg / 56;
        const int hh0 = (tg - bb * 56) * 2;
        char* buf = ldsc + (i & 1) * TILEB;

        f32x4 acc[2][7];
        #pragma unroll
        for (int mf = 0; mf < 2; ++mf)
            #pragma unroll
            for (int nf = 0; nf < 7; ++nf) acc[mf][nf] = zero;

        #pragma unroll
        for (int tt = 0; tt < 9; ++tt) {
            const int kh = tt / 3;
            const int kw = tt - kh * 3;
            const int r  = wn + kh;                           // tile row 0..3
            const int pix0 = r * XW + kw + l16;
            const int hash = (2 * (hh0 + r) + kw + l16) & 7;  // nf-invariant
            const int ba0 = (pix0 << 7) + ((lhi ^ hash) << 4);

            __builtin_amdgcn_s_setprio(1);
            #pragma unroll
            for (int nf = 0; nf < 7; ++nf) {
                short8 bf = *(const short8*)(buf + ba0 + nf * 2048);
                acc[0][nf] = MFMA16(bf, areg[2 * tt][0], acc[0][nf]);
                acc[1][nf] = MFMA16(bf, areg[2 * tt][1], acc[1][nf]);
            }
            __builtin_amdgcn_s_setprio(0);

            __builtin_amdgcn_s_setprio(1);
            #pragma unroll
            for (int nf = 0; nf < 7; ++nf) {
                short8 bf = *(const short8*)(buf + (ba0 ^ 0x40) + nf * 2048);
                acc[0][nf] = MFMA16(bf, areg[2 * tt + 1][0], acc[0][nf]);
                acc[1][nf] = MFMA16(bf, areg[2 * tt + 1][1], acc[1][nf]);
            }
            __builtin_amdgcn_s_setprio(0);
        }

        // epilogue: D row = pixel (lhi*4+j), col = cout (l16); 14 dwordx4 stores
        #pragma unroll
        for (int mf = 0; mf < 2; ++mf) {
            const int o = wm * 32 + mf * 16 + l16;
            const float bv = mf ? bv1 : bv0;
            float* po = out + ((size_t)bb * COUT + o) * (OH * OW) + (hh0 + wn) * OW;
            #pragma unroll
            for (int nf = 0; nf < 7; ++nf) {
                f32x4 v = acc[mf][nf];
                v[0] += bv; v[1] += bv; v[2] += bv; v[3] += bv;
                *(f32x4*)(po + nf * 16 + lhi * 4) = v;
            }
        }

        // counted-vmcnt barrier: in-loop vmem per wave = 7|8 staging + 14 stores.
        // vmcnt(14) retires the (oldest) staging ops; stores drain in background.
        __builtin_amdgcn_sched_barrier(0);
        asm volatile("s_waitcnt vmcnt(14) lgkmcnt(0)" ::: "memory");
        __builtin_amdgcn_sched_barrier(0);
        __builtin_amdgcn_s_barrier();
    }
}

// ---------------- fallback (R0 kernel, needs only 147456 B ws) ----------------

#define BK 32
#define NSTEP 18
#define LDB 40

__global__ __launch_bounds__(256) void wcvt_ident(const float* __restrict__ w,
                                                  u16* __restrict__ wbf) {
    int i = blockIdx.x * 256 + threadIdx.x;
    if (i < COUT * KTOT) wbf[i] = f2bf(w[i]);
}

__global__ __launch_bounds__(256) void conv_fb(const float* __restrict__ x,
                                               const u16* __restrict__ wbf,
                                               const float* __restrict__ bias,
                                               float* __restrict__ out) {
    __shared__ u16 ldsB[OW * LDB];
    const int tid = threadIdx.x;
    int bid = blockIdx.x;
    { int xcd = bid & 7; bid = xcd * 448 + (bid >> 3); }
    const int b = bid / OH;
    const int h = bid - b * OH;
    const float* xbp = x + (size_t)b * (CINC * XH * XW);
    float* outb = out + (size_t)b * (COUT * OH * OW) + h * OW;
    const int lane = tid & 63, wv = tid >> 6, l16 = lane & 15, lhi = lane >> 4;
    const int m0 = wv * 32;
    const int sk = tid >> 3, sn0 = (tid & 7) * 14;
    f32x4 acc[2][7];
    const f32x4 zero = {0.f, 0.f, 0.f, 0.f};
    #pragma unroll
    for (int i = 0; i < 2; ++i)
        #pragma unroll
        for (int j = 0; j < 7; ++j) acc[i][j] = zero;
    for (int t = 0; t < NSTEP; ++t) {
        const int kg = t * BK + sk;
        const int ci = kg / 9;
        const int r9 = kg - ci * 9;
        const int kh = r9 / 3, kw = r9 - (r9 / 3) * 3;
        const float* src = xbp + ((size_t)ci * XH + (h + kh)) * XW + kw + sn0;
        __syncthreads();
        #pragma unroll
        for (int i = 0; i < 14; ++i) ldsB[(sn0 + i) * LDB + sk] = f2bf(src[i]);
        __syncthreads();
        short8 afrag[2];
        #pragma unroll
        for (int mf = 0; mf < 2; ++mf)
            afrag[mf] = *(const short8*)(wbf + (m0 + mf * 16 + l16) * KTOT + t * BK + lhi * 8);
        #pragma unroll
        for (int nf = 0; nf < 7; ++nf) {
            short8 bfrag = *(const short8*)&ldsB[(nf * 16 + l16) * LDB + lhi * 8];
            acc[0][nf] = MFMA16(afrag[0], bfrag, acc[0][nf]);
            acc[1][nf] = MFMA16(afrag[1], bfrag, acc[1][nf]);
        }
    }
    #pragma unroll
    for (int mf = 0; mf < 2; ++mf)
        #pragma unroll
        for (int j = 0; j < 4; ++j) {
            const int o = m0 + mf * 16 + lhi * 4 + j;
            const float bv = bias[o];
            #pragma unroll
            for (int nf = 0; nf < 7; ++nf)
                outb[(size_t)o * (OH * OW) + nf * 16 + l16] = acc[mf][nf][j] + bv;
        }
}

extern "C" void kernel_launch(void* const* d_in, const int* in_sizes, int n_in,
                              void* d_out, int out_size, void* d_ws, size_t ws_size,
                              hipStream_t stream) {
    const float* x    = (const float*)d_in[0];
    const float* w    = (const float*)d_in[3];
    const float* bias = (const float*)d_in[4];
    float* out = (float*)d_out;

    const size_t WBYTES = (size_t)COUT * KTOT * 2;                 // 147456
    const size_t XBYTES = (size_t)NB * XH * XW * CINC * 2;         // 53231616
    if (ws_size >= WBYTES + XBYTES) {
        u16* wbf = (u16*)d_ws;
        u16* xb  = (u16*)((char*)d_ws + WBYTES);
        prep<<<NB * XH + (COUT * KTOT) / 256, 256, 0, stream>>>(x, w, xb, wbf);
        conv_pers2<<<256, 512, 0, stream>>>(xb, wbf, bias, out);
    } else {
        u16* wbf = (u16*)d_ws;
        wcvt_ident<<<(COUT * KTOT + 255) / 256, 256, 0, stream>>>(w, wbf);
        conv_fb<<<NB * OH, 256, 0, stream>>>(x, wbf, bias, out);
    }
}

// Round 10
// 110.455 us; speedup vs baseline: 1.7292x; 1.0948x over previous
//
#include <hip/hip_runtime.h>

typedef __attribute__((ext_vector_type(8))) short short8;
typedef __attribute__((ext_vector_type(4))) float f32x4;
typedef __attribute__((ext_vector_type(4))) unsigned int u32x4;
typedef unsigned short u16;
typedef unsigned int u32;

#define XH 114
#define XW 114
#define CINC 64
#define COUT 128
#define OH 112
#define OW 112
#define NB 32
#define KTOT 576      // CIN*9
#define ROWB 14592    // one input row in LDS: 114*64*2 bytes

static __device__ __forceinline__ u16 f2bf(float f) {
    u32 x = __float_as_uint(f);
    u32 r = (x + 0x7fffu + ((x >> 16) & 1u)) >> 16;
    return (u16)r;
}

#define MFMA16(a, b, c) __builtin_amdgcn_mfma_f32_16x16x32_bf16((a), (b), (c), 0, 0, 0)

static __device__ __forceinline__ void gload16(const void* g, void* l) {
    __builtin_amdgcn_global_load_lds(
        (const __attribute__((address_space(1))) unsigned int*)g,
        (__attribute__((address_space(3))) unsigned int*)l, 16, 0, 0);
}

// ---------------- fast path ----------------

// Merged pre-pass. Blocks [0,3648): x NCHW f32 -> xb bf16, swizzle baked:
//   xb[(b*114+h)*7296 + w*64 + (c8 ^ ((2h+w)&7))*8 + e] = x[b][8*c8+e][h][w]
// Blocks [3648,3936): weights -> bf16, K reordered to (kh,kw,ci).
__global__ __launch_bounds__(256) void prep(const float* __restrict__ x,
                                            const float* __restrict__ w,
                                            u16* __restrict__ xb,
                                            u16* __restrict__ wbf) {
    const int tid = threadIdx.x;
    const int blk = blockIdx.x;
    if (blk >= NB * XH) {
        int i = (blk - NB * XH) * 256 + tid;   // 73728 total, exact
        int o = i / KTOT;
        int rem = i - o * KTOT;
        int khkw = rem >> 6;
        int ci = rem & 63;
        wbf[i] = f2bf(w[(o * CINC + ci) * 9 + khkw]);
        return;
    }
    __shared__ u16 tile[XW * 70];   // [w][ci], u16 stride 70 (dword 35, coprime 32)
    const int b = blk / XH;
    const int h = blk - b * XH;

    #pragma unroll
    for (int it = 0; it < 15; ++it) {
        int idx = it * 256 + tid;
        if (idx < 32 * XW) {
            int cp = idx / XW;                  // 0..31
            int w_ = idx - cp * XW;
            const float* s0 = x + ((size_t)(b * CINC + 2 * cp) * XH + h) * XW + w_;
            float a = s0[0];
            float c = s0[XH * XW];
            u32 pk = (u32)f2bf(a) | ((u32)f2bf(c) << 16);
            *(u32*)&tile[w_ * 70 + 2 * cp] = pk;
        }
    }
    __syncthreads();

    u16* dstrow = xb + (size_t)(b * XH + h) * (XW * CINC);
    #pragma unroll
    for (int p2 = 0; p2 < 4; ++p2) {
        int task = p2 * 256 + tid;
        if (task < XW * 8) {
            int w_ = task >> 3;
            int c8 = task & 7;
            const u32* s = (const u32*)&tile[w_ * 70 + c8 * 8];
            u32x4 v = {s[0], s[1], s[2], s[3]};
            int slot = c8 ^ ((2 * h + w_) & 7);
            *(u32x4*)(dstrow + w_ * CINC + slot * 8) = v;
        }
    }
}

// Ring-buffer conv: 512 blocks x 256 thr (4 waves = 4 cout-groups), 2 blocks/CU
// with INDEPENDENT barriers. Each block: 7 single-row tiles of one batch.
// LDS = 4 row slots (slot = input_row & 3); one new row staged per tile.
// A (weights) in registers; op-swapped MFMA; counted-vmcnt barrier.
__global__ __launch_bounds__(256, 2) void conv_ring(const u16* __restrict__ xb,
                                                    const u16* __restrict__ wbf,
                                                    const float* __restrict__ bias,
                                                    float* __restrict__ out) {
    __shared__ u16 lds[4 * XW * CINC];   // 58368 B
    char* ldsc = (char*)lds;

    const int tid  = threadIdx.x;
    const int lane = tid & 63;
    const int wv   = tid >> 6;        // 0..3 = cout group
    const int l16  = lane & 15;
    const int lhi  = lane >> 4;

    int bidx = blockIdx.x;
    { int xcd = bidx & 7; bidx = xcd * 64 + (bidx >> 3); }   // 512 = 8*64 bijective
    const int bb = bidx >> 4;          // batch 0..31
    const int h0 = (bidx & 15) * 7;    // first output row

    // ---- prologue: weights + bias in registers ----
    const u16* wrow0 = wbf + (wv * 32 + l16) * KTOT + lhi * 8;
    const u16* wrow1 = wrow0 + 16 * KTOT;
    short8 areg0[18], areg1[18];
    #pragma unroll
    for (int t = 0; t < 18; ++t) {
        areg0[t] = *(const short8*)(wrow0 + t * 32);
        areg1[t] = *(const short8*)(wrow1 + t * 32);
    }
    const float bv0 = bias[wv * 32 + l16];
    const float bv1 = bias[wv * 32 + 16 + l16];

    // STAGE one input row into its ring slot: 15 chunks of 1024B (last = 256B)
    // wave wv takes chunks it*4+wv; LDS dest wave-uniform, global src +lane*16.
    auto STAGE = [&](int hin) {
        const char* src = (const char*)(xb + (size_t)(bb * XH + hin) * (XW * CINC));
        char* dst = ldsc + (hin & 3) * ROWB;
        #pragma unroll
        for (int it = 0; it < 4; ++it) {
            const int c = it * 4 + wv;
            const int off = c * 1024;
            if (c < 14) {
                gload16(src + off + lane * 16, dst + off);
            } else if (c == 14) {
                if (lane < 16) gload16(src + off + lane * 16, dst + off);
            }
        }
    };

    STAGE(h0); STAGE(h0 + 1); STAGE(h0 + 2);
    __builtin_amdgcn_sched_barrier(0);
    asm volatile("s_waitcnt vmcnt(0) lgkmcnt(0)" ::: "memory");
    __builtin_amdgcn_sched_barrier(0);
    __builtin_amdgcn_s_barrier();

    const f32x4 zero = {0.f, 0.f, 0.f, 0.f};

    #pragma unroll 1
    for (int i = 0; i < 7; ++i) {
        const int hrow = h0 + i;
        // stage next-needed row (slot (hrow+3)&3 is disjoint from read slots)
        if (i < 6) STAGE(hrow + 3);

        f32x4 acc[2][7];
        #pragma unroll
        for (int mf = 0; mf < 2; ++mf)
            #pragma unroll
            for (int nf = 0; nf < 7; ++nf) acc[mf][nf] = zero;

        #pragma unroll
        for (int tt = 0; tt < 9; ++tt) {
            const int kh = tt / 3;
            const int kw = tt - kh * 3;
            const int hin = hrow + kh;                       // input row
            const int sb  = (hin & 3) * ROWB;
            const int hash = (2 * hin + kw + l16) & 7;       // nf-invariant
            const int ba0 = sb + ((kw + l16) << 7) + ((lhi ^ hash) << 4);

            #pragma unroll
            for (int nf = 0; nf < 7; ++nf) {
                short8 bf = *(const short8*)(ldsc + ba0 + nf * 2048);
                acc[0][nf] = MFMA16(bf, areg0[2 * tt], acc[0][nf]);
                acc[1][nf] = MFMA16(bf, areg1[2 * tt], acc[1][nf]);
            }
            #pragma unroll
            for (int nf = 0; nf < 7; ++nf) {
                short8 bf = *(const short8*)(ldsc + (ba0 ^ 0x40) + nf * 2048);
                acc[0][nf] = MFMA16(bf, areg0[2 * tt + 1], acc[0][nf]);
                acc[1][nf] = MFMA16(bf, areg1[2 * tt + 1], acc[1][nf]);
            }
        }

        // epilogue: D row = pixel (lhi*4+j), col = cout (l16); 14 dwordx4 stores
        #pragma unroll
        for (int mf = 0; mf < 2; ++mf) {
            const int o = wv * 32 + mf * 16 + l16;
            const float bv = mf ? bv1 : bv0;
            float* po = out + ((size_t)bb * COUT + o) * (OH * OW) + hrow * OW;
            #pragma unroll
            for (int nf = 0; nf < 7; ++nf) {
                f32x4 v = acc[mf][nf];
                v[0] += bv; v[1] += bv; v[2] += bv; v[3] += bv;
                *(f32x4*)(po + nf * 16 + lhi * 4) = v;
            }
        }

        // counted barrier: outstanding = old stores(<=14) + stage(<=4) + stores(14);
        // vmcnt(14) retires old stores + this tile's staging; new stores float.
        __builtin_amdgcn_sched_barrier(0);
        asm volatile("s_waitcnt vmcnt(14) lgkmcnt(0)" ::: "memory");
        __builtin_amdgcn_sched_barrier(0);
        __builtin_amdgcn_s_barrier();
    }
}

// ---------------- fallback (R0 kernel, needs only 147456 B ws) ----------------

#define BK 32
#define NSTEP 18
#define LDB 40

__global__ __launch_bounds__(256) void wcvt_ident(const float* __restrict__ w,
                                                  u16* __restrict__ wbf) {
    int i = blockIdx.x * 256 + threadIdx.x;
    if (i < COUT * KTOT) wbf[i] = f2bf(w[i]);
}

__global__ __launch_bounds__(256) void conv_fb(const float* __restrict__ x,
                                               const u16* __restrict__ wbf,
                                               const float* __restrict__ bias,
                                               float* __restrict__ out) {
    __shared__ u16 ldsB[OW * LDB];
    const int tid = threadIdx.x;
    int bid = blockIdx.x;
    { int xcd = bid & 7; bid = xcd * 448 + (bid >> 3); }
    const int b = bid / OH;
    const int h = bid - b * OH;
    const float* xbp = x + (size_t)b * (CINC * XH * XW);
    float* outb = out + (size_t)b * (COUT * OH * OW) + h * OW;
    const int lane = tid & 63, wv = tid >> 6, l16 = lane & 15, lhi = lane >> 4;
    const int m0 = wv * 32;
    const int sk = tid >> 3, sn0 = (tid & 7) * 14;
    f32x4 acc[2][7];
    const f32x4 zero = {0.f, 0.f, 0.f, 0.f};
    #pragma unroll
    for (int i = 0; i < 2; ++i)
        #pragma unroll
        for (int j = 0; j < 7; ++j) acc[i][j] = zero;
    for (int t = 0; t < NSTEP; ++t) {
        const int kg = t * BK + sk;
        const int ci = kg / 9;
        const int r9 = kg - ci * 9;
        const int kh = r9 / 3, kw = r9 - (r9 / 3) * 3;
        const float* src = xbp + ((size_t)ci * XH + (h + kh)) * XW + kw + sn0;
        __syncthreads();
        #pragma unroll
        for (int i = 0; i < 14; ++i) ldsB[(sn0 + i) * LDB + sk] = f2bf(src[i]);
        __syncthreads();
        short8 afrag[2];
        #pragma unroll
        for (int mf = 0; mf < 2; ++mf)
            afrag[mf] = *(const short8*)(wbf + (m0 + mf * 16 + l16) * KTOT + t * BK + lhi * 8);
        #pragma unroll
        for (int nf = 0; nf < 7; ++nf) {
            short8 bfrag = *(const short8*)&ldsB[(nf * 16 + l16) * LDB + lhi * 8];
            acc[0][nf] = MFMA16(afrag[0], bfrag, acc[0][nf]);
            acc[1][nf] = MFMA16(afrag[1], bfrag, acc[1][nf]);
        }
    }
    #pragma unroll
    for (int mf = 0; mf < 2; ++mf)
        #pragma unroll
        for (int j = 0; j < 4; ++j) {
            const int o = m0 + mf * 16 + lhi * 4 + j;
            const float bv = bias[o];
            #pragma unroll
            for (int nf = 0; nf < 7; ++nf)
                outb[(size_t)o * (OH * OW) + nf * 16 + l16] = acc[mf][nf][j] + bv;
        }
}

extern "C" void kernel_launch(void* const* d_in, const int* in_sizes, int n_in,
                              void* d_out, int out_size, void* d_ws, size_t ws_size,
                              hipStream_t stream) {
    const float* x    = (const float*)d_in[0];
    const float* w    = (const float*)d_in[3];
    const float* bias = (const float*)d_in[4];
    float* out = (float*)d_out;

    const size_t WBYTES = (size_t)COUT * KTOT * 2;                 // 147456
    const size_t XBYTES = (size_t)NB * XH * XW * CINC * 2;         // 53231616
    if (ws_size >= WBYTES + XBYTES) {
        u16* wbf = (u16*)d_ws;
        u16* xb  = (u16*)((char*)d_ws + WBYTES);
        prep<<<NB * XH + (COUT * KTOT) / 256, 256, 0, stream>>>(x, w, xb, wbf);
        conv_ring<<<512, 256, 0, stream>>>(xb, wbf, bias, out);
    } else {
        u16* wbf = (u16*)d_ws;
        wcvt_ident<<<(COUT * KTOT + 255) / 256, 256, 0, stream>>>(w, wbf);
        conv_fb<<<NB * OH, 256, 0, stream>>>(x, wbf, bias, out);
    }
}